// Round 2
// baseline (496.711 us; speedup 1.0000x reference)
//
#include <hip/hip_runtime.h>
#include <stdint.h>

// Problem: B=32, T=128, C=64, DIN=DOUT=32, 4 gates. Channels are fully
// independent LSTMs; batch shares per-(t,c) weights.
#define T_STEPS 128
#define C_CH    64
#define D_IN    32
#define D_OUT   32

#define RS 72   // bf16 LDS plane row stride in shorts (64 data + 8 pad)
#define ES 34   // exch row stride in floats (keeps all phases <=2-way banks)

using frag_ab = __attribute__((ext_vector_type(8))) short;  // 8 bf16
using frag_cd = __attribute__((ext_vector_type(4))) float;  // 4 fp32 acc

// Barrier draining only LDS (lgkmcnt) so global prefetch loads stay in
// flight across the per-step barriers (avoids __syncthreads' vmcnt(0) drain).
__device__ __forceinline__ void lds_barrier() {
  asm volatile("s_waitcnt lgkmcnt(0)\n\ts_barrier" ::: "memory");
}

// low short = u0[31:16], high short = u1[31:16]
__device__ __forceinline__ uint32_t pack_hi16(uint32_t u0, uint32_t u1) {
  return __builtin_amdgcn_perm(u1, u0, 0x07060302u);
}

__device__ __forceinline__ float fast_sigmoid(float v) {
  return __builtin_amdgcn_rcpf(1.0f + __expf(-v));
}
__device__ __forceinline__ float fast_tanh(float v) {
  return fmaf(2.0f, __builtin_amdgcn_rcpf(1.0f + __expf(-2.0f * v)), -1.0f);
}

// Grid: 64 WGs, one per channel -> each weight byte read exactly once.
// Block: 512 threads = 8 waves. wave = gate(4) x batch-half(2); MFMA N=16
// fully populated (batch rows bh*16 .. bh*16+15).
__global__ void __launch_bounds__(512, 2)
lstm_kernel(const float* __restrict__ x, const float* __restrict__ xOps,
            const float* __restrict__ hOps, float* __restrict__ out) {
  __shared__ short Ahi[128 * RS];   // weights hi-bf16; rows m = g*32+i, k in [0,64)
  __shared__ short Alo[128 * RS];   // weights lo-bf16 (residual)
  __shared__ short Bhi[32 * RS];    // [x_t ; h] hi; row n = batch b (all 32)
  __shared__ short Blo[32 * RS];
  __shared__ float exch[4 * 32 * ES];  // gate pre-activations [g][i]*ES + b

  const int tid = threadIdx.x;
  const int c   = blockIdx.x;       // channel

  // Zero B planes (h part must start at 0; x part is overwritten every step).
  for (int idx = tid; idx < (32 * RS) / 2; idx += 512) {
    ((uint32_t*)Bhi)[idx] = 0u;
    ((uint32_t*)Blo)[idx] = 0u;
  }

  // Weight staging addresses (t-invariant): 8192 floats/step = 512 thr x 4 float4.
  const float* wptr[4];
  int wlds[4];
#pragma unroll
  for (int it = 0; it < 4; ++it) {
    int f  = (it * 512 + tid) * 4;  // flat float idx in [0, 8192)
    int fh = f & 4095;
    int g  = fh >> 10;
    int i  = (fh >> 5) & 31;
    int j  = fh & 31;               // multiple of 4
    const float* base = (f < 4096) ? xOps : hOps;
    wptr[it] = base + (size_t)g * (T_STEPS * C_CH * 1024) + (size_t)c * 1024 + i * 32 + j;
    wlds[it] = (g * 32 + i) * RS + j + ((f < 4096) ? 0 : 32);
  }

  // x staging: 1024 floats/step = 512 thr x float2. bl = batch 0..31.
  const int bl = tid >> 4;
  const int kp = (tid & 15) * 2;
  const float* xptr = x + (size_t)bl * (T_STEPS * C_CH * D_IN) + (size_t)c * D_IN + kp;
  const int xlds = bl * RS + kp;

  const int wave = tid >> 6;
  const int lane = tid & 63;
  const int g    = wave & 3;        // gate
  const int bh   = wave >> 2;       // batch half
  const int fn   = lane & 15;
  const int quad = lane >> 4;

  const int ei  = tid & 31;         // elementwise: output dim
  const int eb0 = tid >> 5;         // elementwise: batch 0..15 (also handles +16)

  auto load = [&](float4 wv[4], float2& xv, int t) {
#pragma unroll
    for (int it = 0; it < 4; ++it)
      wv[it] = *(const float4*)(wptr[it] + (size_t)t * (C_CH * 1024));
    xv = *(const float2*)(xptr + (size_t)t * (C_CH * D_IN));
  };

  auto stage = [&](const float4 wv[4], float2 xv) {
    // fp32 -> (hi,lo) bf16 split: hi = trunc16(f), lo = trunc16(f - hi).
#pragma unroll
    for (int it = 0; it < 4; ++it) {
      float4 v = wv[it];
      uint32_t u0 = __float_as_uint(v.x), u1 = __float_as_uint(v.y);
      uint32_t u2 = __float_as_uint(v.z), u3 = __float_as_uint(v.w);
      float r0 = v.x - __uint_as_float(u0 & 0xFFFF0000u);
      float r1 = v.y - __uint_as_float(u1 & 0xFFFF0000u);
      float r2 = v.z - __uint_as_float(u2 & 0xFFFF0000u);
      float r3 = v.w - __uint_as_float(u3 & 0xFFFF0000u);
      int s = wlds[it];
      *(uint2*)&Ahi[s] = make_uint2(pack_hi16(u0, u1), pack_hi16(u2, u3));
      *(uint2*)&Alo[s] = make_uint2(pack_hi16(__float_as_uint(r0), __float_as_uint(r1)),
                                    pack_hi16(__float_as_uint(r2), __float_as_uint(r3)));
    }
    uint32_t u0 = __float_as_uint(xv.x), u1 = __float_as_uint(xv.y);
    float r0 = xv.x - __uint_as_float(u0 & 0xFFFF0000u);
    float r1 = xv.y - __uint_as_float(u1 & 0xFFFF0000u);
    *(uint32_t*)&Bhi[xlds] = pack_hi16(u0, u1);
    *(uint32_t*)&Blo[xlds] = pack_hi16(__float_as_uint(r0), __float_as_uint(r1));
  };

  // Prefetch t=0 and t=1 (2-deep: ~72 KB in flight/WG covers HBM latency).
  float4 wv0[4], wv1[4];
  float2 xv0, xv1;
  load(wv0, xv0, 0);
  load(wv1, xv1, 1);

  lds_barrier();  // order B-zeroing before first h reads

  float cs0 = 0.0f, cs1 = 0.0f;  // cell state for b=eb0 and b=eb0+16

#pragma unroll 1
  for (int t = 0; t < T_STEPS; ++t) {
    if ((t & 1) == 0) {
      stage(wv0, xv0);
      if (t + 2 < T_STEPS) load(wv0, xv0, t + 2);
    } else {
      stage(wv1, xv1);
      if (t + 2 < T_STEPS) load(wv1, xv1, t + 2);
    }

    lds_barrier();

    // X[g] = [xop_g | hop_g] * [x_t ; h], 3-term hi/lo split, M=32 N=16 K=64.
    frag_cd acc0 = {0.f, 0.f, 0.f, 0.f};
    frag_cd acc1 = {0.f, 0.f, 0.f, 0.f};
#pragma unroll
    for (int kt = 0; kt < 2; ++kt) {
      const int kk = kt * 32 + quad * 8;
      frag_ab bhf = *(const frag_ab*)&Bhi[(bh * 16 + fn) * RS + kk];
      frag_ab blf = *(const frag_ab*)&Blo[(bh * 16 + fn) * RS + kk];
      {
        int m = g * 32 + fn;
        frag_ab ah = *(const frag_ab*)&Ahi[m * RS + kk];
        frag_ab al = *(const frag_ab*)&Alo[m * RS + kk];
        acc0 = __builtin_amdgcn_mfma_f32_16x16x32_bf16(ah, bhf, acc0, 0, 0, 0);
        acc0 = __builtin_amdgcn_mfma_f32_16x16x32_bf16(ah, blf, acc0, 0, 0, 0);
        acc0 = __builtin_amdgcn_mfma_f32_16x16x32_bf16(al, bhf, acc0, 0, 0, 0);
      }
      {
        int m = g * 32 + 16 + fn;
        frag_ab ah = *(const frag_ab*)&Ahi[m * RS + kk];
        frag_ab al = *(const frag_ab*)&Alo[m * RS + kk];
        acc1 = __builtin_amdgcn_mfma_f32_16x16x32_bf16(ah, bhf, acc1, 0, 0, 0);
        acc1 = __builtin_amdgcn_mfma_f32_16x16x32_bf16(ah, blf, acc1, 0, 0, 0);
        acc1 = __builtin_amdgcn_mfma_f32_16x16x32_bf16(al, bhf, acc1, 0, 0, 0);
      }
    }

    // Gate exchange. C/D layout: col(n)=lane&15, row=quad*4+r. All 16 cols valid.
#pragma unroll
    for (int r = 0; r < 4; ++r) {
      exch[(g * 32 + quad * 4 + r) * ES + bh * 16 + fn]      = acc0[r];
      exch[(g * 32 + 16 + quad * 4 + r) * ES + bh * 16 + fn] = acc1[r];
    }

    lds_barrier();

    // Elementwise cell update; thread (eb0, ei) owns b=eb0 and b=eb0+16.
#pragma unroll
    for (int half = 0; half < 2; ++half) {
      const int b = eb0 + half * 16;
      float X0 = exch[(0 * 32 + ei) * ES + b];
      float X1 = exch[(1 * 32 + ei) * ES + b];
      float X2 = exch[(2 * 32 + ei) * ES + b];
      float X3 = exch[(3 * 32 + ei) * ES + b];
      float ig = fast_sigmoid(X0);
      float fg = fast_sigmoid(X1);
      float gg = fast_tanh(X2);
      float og = fast_sigmoid(X3);
      float& cs = half ? cs1 : cs0;
      cs = fg * cs + ig * gg;
      float hval = og * fast_tanh(cs);
      if (t == T_STEPS - 1) {
        out[((size_t)b * C_CH + c) * D_OUT + ei] = hval;
      } else {
        // h -> B rows k=32+i as packed hi/lo bf16 (pair via shfl with ei^1)
        uint32_t u   = __float_as_uint(hval);
        float    rr  = hval - __uint_as_float(u & 0xFFFF0000u);
        uint32_t ru  = __float_as_uint(rr);
        uint32_t pu  = __shfl_xor(u, 1, 64);
        uint32_t pru = __shfl_xor(ru, 1, 64);
        if ((ei & 1) == 0) {
          *(uint32_t*)&Bhi[b * RS + 32 + ei] = pack_hi16(u, pu);
          *(uint32_t*)&Blo[b * RS + 32 + ei] = pack_hi16(ru, pru);
        }
      }
    }
    // h writes are ordered before next iteration's MFMA reads by the next
    // iteration's first lds_barrier; next staging touches disjoint LDS.
  }
}

extern "C" void kernel_launch(void* const* d_in, const int* in_sizes, int n_in,
                              void* d_out, int out_size, void* d_ws, size_t ws_size,
                              hipStream_t stream) {
  const float* x    = (const float*)d_in[0];
  const float* xOps = (const float*)d_in[1];
  const float* hOps = (const float*)d_in[2];
  lstm_kernel<<<dim3(C_CH), dim3(512), 0, stream>>>(x, xOps, hOps, (float*)d_out);
}